// Round 7
// baseline (297.005 us; speedup 1.0000x reference)
//
#include <hip/hip_runtime.h>
#include <math.h>

#define DIN   512
#define TSEQ  2048
#define BATCH 4
#define NH    8
#define DHEAD 64
#define MTOT  8192   // BATCH*TSEQ

typedef __attribute__((ext_vector_type(8))) __bf16 bf16x8;
typedef __attribute__((ext_vector_type(8))) short  s16x8;
typedef __attribute__((ext_vector_type(4))) float  f32x4;

__device__ __forceinline__ unsigned short f2b(float f) {
  union { float f; unsigned int u; } c; c.f = f;
  unsigned int r = (c.u + 0x7fffu + ((c.u >> 16) & 1u)) >> 16;
  return (unsigned short)r;
}

__device__ __forceinline__ float b2f(unsigned short u) {
  union { unsigned int i; float f; } c; c.i = (unsigned int)u << 16; return c.f;
}

__device__ __forceinline__ unsigned int pkbf(float a, float b) {
  union { __bf16 h[2]; unsigned int u; } c;
  c.h[0] = (__bf16)a; c.h[1] = (__bf16)b; return c.u;
}

__device__ __forceinline__ f32x4 mfma16(bf16x8 a, bf16x8 b, f32x4 c) {
  return __builtin_amdgcn_mfma_f32_16x16x32_bf16(a, b, c, 0, 0, 0);
}

// async global->LDS, 16B per lane; LDS dest = wave-uniform base + lane*16.
__device__ __forceinline__ void gload16(const void* gsrc, void* ldsbase) {
  __builtin_amdgcn_global_load_lds(
      (const __attribute__((address_space(1))) unsigned int*)gsrc,
      (__attribute__((address_space(3))) unsigned int*)(unsigned int)(unsigned long long)ldsbase,
      16, 0, 0);
}

#define VMCNT0_BARRIER() do { \
    asm volatile("s_waitcnt vmcnt(0)" ::: "memory"); \
    __builtin_amdgcn_s_barrier(); } while (0)

// ---------------------------------------------------------------- cast f32->bf16 (3 tensors)
__global__ __launch_bounds__(256) void cast3_kernel(const float* __restrict__ q,
                                                    const float* __restrict__ k,
                                                    const float* __restrict__ v,
                                                    unsigned short* __restrict__ oq,
                                                    unsigned short* __restrict__ ok,
                                                    unsigned short* __restrict__ ov) {
  const float* in = blockIdx.y == 0 ? q : blockIdx.y == 1 ? k : v;
  unsigned short* out = blockIdx.y == 0 ? oq : blockIdx.y == 1 ? ok : ov;
  int i = (blockIdx.x * 256 + threadIdx.x) * 8;
  float4 a = *(const float4*)(in + i);
  float4 b = *(const float4*)(in + i + 4);
  ushort4 u0, u1;
  u0.x = f2b(a.x); u0.y = f2b(a.y); u0.z = f2b(a.z); u0.w = f2b(a.w);
  u1.x = f2b(b.x); u1.y = f2b(b.y); u1.z = f2b(b.z); u1.w = f2b(b.w);
  *(ushort4*)(out + i) = u0;
  *(ushort4*)(out + i + 4) = u1;
}

// ---------------------------- 6x W [K][N] f32 -> Wt [N][K] bf16 (one launch)
__global__ __launch_bounds__(256) void transpose6_kernel(const float* __restrict__ w0,
                                                         const float* __restrict__ w1,
                                                         const float* __restrict__ w2,
                                                         const float* __restrict__ w3,
                                                         const float* __restrict__ w4,
                                                         const float* __restrict__ w5,
                                                         unsigned short* __restrict__ Wt) {
  const float* W;
  switch (blockIdx.z) {
    case 0: W = w0; break; case 1: W = w1; break; case 2: W = w2; break;
    case 3: W = w3; break; case 4: W = w4; break; default: W = w5; break;
  }
  unsigned short* dst = Wt + (size_t)blockIdx.z * 512 * 512;
  __shared__ float tile[32][33];
  int bx = blockIdx.x * 32, by = blockIdx.y * 32;
  int tx = threadIdx.x & 31, ty = threadIdx.x >> 5;
  #pragma unroll
  for (int yy = ty; yy < 32; yy += 8)
    tile[yy][tx] = W[(size_t)(by + yy) * DIN + bx + tx];
  __syncthreads();
  #pragma unroll
  for (int yy = ty; yy < 32; yy += 8)
    dst[(size_t)(bx + yy) * DIN + by + tx] = f2b(tile[tx][yy]);
}

// ---------------------------------------------------------------- GEMM core
// BM=64, BN=64, BK=32, 16 K-steps; 4 waves (2x2), wave tile 32x32, acc 2x2.
// 16KB LDS 2-buf -> whole 1024-block grid co-resident (4 blk/CU, 16 waves/CU).
// BK=32 row stride (64B) is bank-conflict-free for b128 frag reads: no swizzle.
__device__ __forceinline__ void gemm_core(const unsigned short* __restrict__ A,
                                          const unsigned short* __restrict__ Bt,
                                          int m0, int n0,
                                          unsigned short (*Als)[64 * 32],
                                          unsigned short (*Bls)[64 * 32],
                                          f32x4 (*acc)[2]) {
  const int tid = threadIdx.x, lane = tid & 63, w = tid >> 6;
  const int wr = w >> 1, wc = w & 1;
  const int l = lane & 15, g = lane >> 4;
  const int srow = lane >> 2;        // 0..15 rows within one 1KB instr
  const int sce  = (lane & 3) * 8;   // col elems within 32-elem row

  // per wave per step: 1 A-instr + 1 B-instr (each 1KB = 16 rows x 32 elems)
  #define GSTAGE(buf, k0) do { \
      gload16(A  + (size_t)(m0 + w * 16 + srow) * 512 + (k0) + sce, &Als[buf][w * 512]); \
      gload16(Bt + (size_t)(n0 + w * 16 + srow) * 512 + (k0) + sce, &Bls[buf][w * 512]); \
    } while (0)

  GSTAGE(0, 0);
  VMCNT0_BARRIER();
  for (int t = 0; t < 16; ++t) {
    int cur = t & 1;
    if (t < 15) GSTAGE(cur ^ 1, (t + 1) * 32);   // issue next-tile loads FIRST
    bf16x8 af[2], bf[2];
    #pragma unroll
    for (int m = 0; m < 2; ++m)
      af[m] = *(const bf16x8*)(&Als[cur][(wr * 32 + m * 16 + l) * 32 + g * 8]);
    #pragma unroll
    for (int n = 0; n < 2; ++n)
      bf[n] = *(const bf16x8*)(&Bls[cur][(wc * 32 + n * 16 + l) * 32 + g * 8]);
    #pragma unroll
    for (int m = 0; m < 2; ++m)
      #pragma unroll
      for (int n = 0; n < 2; ++n)
        acc[m][n] = mfma16(af[m], bf[n], acc[m][n]);
    VMCNT0_BARRIER();
  }
  #undef GSTAGE
}

enum { EPI_BF16 = 0, EPI_VT = 1, EPI_RESF32 = 2, EPI_RESB16 = 3, EPI_LRELU = 4 };

template <int EPI>
__global__ __launch_bounds__(256) void gemm_kernel(const unsigned short* __restrict__ A,
                                                   const unsigned short* __restrict__ Bt,
                                                   const float* __restrict__ bias,
                                                   const void* __restrict__ res,
                                                   unsigned short* __restrict__ out) {
  __shared__ unsigned short Als[2][64 * 32];
  __shared__ unsigned short Bls[2][64 * 32];
  const int lane = threadIdx.x & 63, w = threadIdx.x >> 6;
  const int wr = w >> 1, wc = w & 1;
  const int l = lane & 15, g = lane >> 4;
  const int m0 = blockIdx.x * 64, n0 = blockIdx.y * 64;
  f32x4 acc[2][2] = {};
  gemm_core(A, Bt, m0, n0, Als, Bls, acc);

  #pragma unroll
  for (int m = 0; m < 2; ++m) {
    int grb = m0 + wr * 32 + m * 16 + g * 4;
    #pragma unroll
    for (int n = 0; n < 2; ++n) {
      int gc = n0 + wc * 32 + n * 16 + l;
      float bv = bias[gc];
      #pragma unroll
      for (int r = 0; r < 4; ++r) {
        int gr = grb + r;
        float v = acc[m][n][r] + bv;
        if (EPI == EPI_RESF32) v += ((const float*)res)[(size_t)gr * 512 + gc];
        if (EPI == EPI_RESB16) v += b2f(((const unsigned short*)res)[(size_t)gr * 512 + gc]);
        if (EPI == EPI_LRELU)  v = v > 0.f ? v : 0.01f * v;
        if (EPI == EPI_VT) {   // Vt[(b*512+gc)][t]
          int b = gr >> 11, t = gr & 2047;
          out[((size_t)(b * 512 + gc) << 11) + t] = f2b(v);
        } else {
          out[(size_t)gr * 512 + gc] = f2b(v);
        }
      }
    }
  }
}

// QKV fused (grid.z selects projection); z=2 writes transposed V.
__global__ __launch_bounds__(256) void gemm_qkv_kernel(const unsigned short* __restrict__ qb,
                                                       const unsigned short* __restrict__ kb,
                                                       const unsigned short* __restrict__ vb,
                                                       const unsigned short* __restrict__ Wt,
                                                       const float* __restrict__ bq,
                                                       const float* __restrict__ bk,
                                                       const float* __restrict__ bv,
                                                       unsigned short* __restrict__ Qp,
                                                       unsigned short* __restrict__ Kp,
                                                       unsigned short* __restrict__ Vt) {
  __shared__ unsigned short Als[2][64 * 32];
  __shared__ unsigned short Bls[2][64 * 32];
  const int z = blockIdx.z;
  const unsigned short* A = z == 0 ? qb : z == 1 ? kb : vb;
  const unsigned short* B = Wt + (size_t)z * 512 * 512;
  const float* bias = z == 0 ? bq : z == 1 ? bk : bv;
  const int lane = threadIdx.x & 63, w = threadIdx.x >> 6;
  const int wr = w >> 1, wc = w & 1;
  const int l = lane & 15, g = lane >> 4;
  const int m0 = blockIdx.x * 64, n0 = blockIdx.y * 64;
  f32x4 acc[2][2] = {};
  gemm_core(A, B, m0, n0, Als, Bls, acc);

  #pragma unroll
  for (int m = 0; m < 2; ++m) {
    int grb = m0 + wr * 32 + m * 16 + g * 4;
    #pragma unroll
    for (int n = 0; n < 2; ++n) {
      int gc = n0 + wc * 32 + n * 16 + l;
      float bvl = bias[gc];
      #pragma unroll
      for (int r = 0; r < 4; ++r) {
        int gr = grb + r;
        float v = acc[m][n][r] + bvl;
        if (z == 0) {
          Qp[(size_t)gr * 512 + gc] = f2b(v);
        } else if (z == 1) {
          Kp[(size_t)gr * 512 + gc] = f2b(v);
        } else {  // transposed: Vt[(b*512+gc)][t]
          int b = gr >> 11, t = gr & 2047;
          Vt[((size_t)(b * 512 + gc) << 11) + t] = f2b(v);
        }
      }
    }
  }
}

// ---------------------------------------------------------------- flash attention
// Grid (bh=32, qt=32), 1024 blocks all co-resident (24KB LDS). K staged in LDS
// (swizzled, 2-buf); V read DIRECT from global (L2-resident, no staging).
// Swapped QK^T; defer-rescale; row sums via ones-MFMA.
__global__ __launch_bounds__(256) void attn_kernel(const unsigned short* __restrict__ Q,
                                                   const unsigned short* __restrict__ K,
                                                   const unsigned short* __restrict__ Vt,
                                                   unsigned short* __restrict__ O) {
  __shared__ unsigned short Kls[2][64 * 64];
  __shared__ unsigned short Pls[4][16 * 64];
  const int tid = threadIdx.x, lane = tid & 63, w = tid >> 6;
  const int l = lane & 15, g = lane >> 4;
  const int bh = blockIdx.x;           // id%8 = bh%8 -> XCD locality
  const int qt = (int)gridDim.y - 1 - (int)blockIdx.y;  // longest first
  const int b = bh >> 3, h = bh & 7;
  const int sx = (l & 7) * 8;          // read-side swizzle (elems)
  const float SC2 = 0.125f * 1.44269504088896340736f;
  const float THR = 64.f;              // raw-score defer threshold (~e^8 bound)

  const int r8 = lane >> 3;
  const int sce = ((lane & 7) ^ r8) * 8;  // inverse-swizzled source col (elems)

  #define STAGEK(buf, kv0) do { \
      _Pragma("unroll") \
      for (int i_ = 0; i_ < 2; ++i_) { \
        int ii_ = w * 2 + i_; \
        gload16(K + (size_t)(b * 2048 + (kv0) + ii_ * 8 + r8) * 512 + h * 64 + sce, \
                &Kls[buf][ii_ * 512]); \
      } } while (0)

  const int q0 = qt * 64 + w * 16;
  bf16x8 qf[2];
  #pragma unroll
  for (int kf = 0; kf < 2; ++kf)
    qf[kf] = *(const bf16x8*)(Q + (size_t)(b * 2048 + q0 + l) * 512 + h * 64 + kf * 32 + g * 8);

  bf16x8 vones;
  #pragma unroll
  for (int i = 0; i < 8; ++i) vones[i] = (__bf16)1.0f;

  float mrun = -1e30f;
  f32x4 o[4] = {};
  f32x4 os = {0.f, 0.f, 0.f, 0.f};

  STAGEK(0, 0);
  VMCNT0_BARRIER();

  for (int s = 0; s <= qt; ++s) {
    int cur = s & 1;
    int kv0 = s * 64;
    if (s < qt) STAGEK(cur ^ 1, kv0 + 64);

    // V fragments direct from global (L2 hit; latency hides under QK+softmax)
    bf16x8 vf[2][4];
    #pragma unroll
    for (int kf = 0; kf < 2; ++kf)
      #pragma unroll
      for (int n = 0; n < 4; ++n)
        vf[kf][n] = *(const bf16x8*)(
            Vt + (size_t)(b * 512 + h * 64 + n * 16 + l) * 2048 + kv0 + kf * 32 + g * 8);

    // S^T (raw): lane holds S[q=q0+l][kv = kv0 + t*16 + g*4 + r]
    f32x4 st[4];
    #pragma unroll
    for (int t = 0; t < 4; ++t) {
      st[t] = f32x4{0.f, 0.f, 0.f, 0.f};
      #pragma unroll
      for (int kf = 0; kf < 2; ++kf) {
        bf16x8 kfr = *(const bf16x8*)(&Kls[cur][(t * 16 + l) * 64 + ((kf * 32 + g * 8) ^ sx)]);
        st[t] = mfma16(kfr, qf[kf], st[t]);
      }
    }
    if (s == qt) {   // only the diagonal step masks
      const int qrow = q0 + l;
      #pragma unroll
      for (int t = 0; t < 4; ++t)
        #pragma unroll
        for (int r = 0; r < 4; ++r)
          if (kv0 + t * 16 + g * 4 + r > qrow) st[t][r] = -1e30f;
    }

    float mx = fmaxf(
        fmaxf(fmaxf(fmaxf(st[0][0], st[0][1]), st[0][2]),
              fmaxf(fmaxf(st[0][3], st[1][0]), st[1][1])),
        fmaxf(fmaxf(fmaxf(st[1][2], st[1][3]), st[2][0]),
              fmaxf(fmaxf(st[2][1], st[2][2]), st[2][3])));
    mx = fmaxf(mx, fmaxf(fmaxf(st[3][0], st[3][1]), fmaxf(st[3][2], st[3][3])));
    mx = fmaxf(mx, __shfl_xor(mx, 16, 64));
    mx = fmaxf(mx, __shfl_xor(mx, 32, 64));

    if (!__all(mx <= mrun + THR)) {   // T13 defer-rescale
      float nm = fmaxf(mrun, mx);
      float alpha = exp2f((mrun - nm) * SC2);
      mrun = nm;
      #pragma unroll
      for (int r = 0; r < 4; ++r) {
        float ar = __shfl(alpha, g * 4 + r, 64);
        #pragma unroll
        for (int n = 0; n < 4; ++n) o[n][r] *= ar;
        os[r] *= ar;
      }
    }

    float mS = mrun * SC2;
    #pragma unroll
    for (int t = 0; t < 4; ++t)
      #pragma unroll
      for (int r = 0; r < 4; ++r)
        st[t][r] = exp2f(fmaf(st[t][r], SC2, -mS));

    // P pack -> swizzled per-wave LDS [16][64], then PV (+ ones for row sums)
    #pragma unroll
    for (int t = 0; t < 4; ++t) {
      uint2 u;
      u.x = pkbf(st[t][0], st[t][1]);
      u.y = pkbf(st[t][2], st[t][3]);
      *(uint2*)(&Pls[w][l * 64 + ((t * 16 + g * 4) ^ sx)]) = u;
    }
    #pragma unroll
    for (int kf = 0; kf < 2; ++kf) {
      bf16x8 pa = *(const bf16x8*)(&Pls[w][l * 64 + ((kf * 32 + g * 8) ^ sx)]);
      #pragma unroll
      for (int n = 0; n < 4; ++n)
        o[n] = mfma16(pa, vf[kf][n], o[n]);
      os = mfma16(pa, vones, os);
    }

    VMCNT0_BARRIER();
  }

  #pragma unroll
  for (int r = 0; r < 4; ++r) {
    float lir = 1.f / os[r];
    #pragma unroll
    for (int n = 0; n < 4; ++n)
      O[(size_t)(b * 2048 + q0 + g * 4 + r) * 512 + h * 64 + n * 16 + l] =
          f2b(o[n][r] * lir);
  }
  #undef STAGEK
}

// ---------------------------------------------------------------- LayerNorm (bf16 in)
template <int OUTF32>
__global__ __launch_bounds__(256) void lnb_kernel(const unsigned short* __restrict__ X,
                                                  const float* __restrict__ g,
                                                  const float* __restrict__ be,
                                                  float* __restrict__ Yf,
                                                  unsigned short* __restrict__ Yb) {
  int row = blockIdx.x * 4 + (threadIdx.x >> 6);
  int lane = threadIdx.x & 63;
  s16x8 v = *(const s16x8*)(X + (size_t)row * 512 + lane * 8);
  float f[8];
  #pragma unroll
  for (int j = 0; j < 8; ++j) f[j] = b2f((unsigned short)v[j]);
  float s = 0.f;
  #pragma unroll
  for (int j = 0; j < 8; ++j) s += f[j];
  #pragma unroll
  for (int t = 1; t < 64; t <<= 1) s += __shfl_xor(s, t, 64);
  float mu = s * (1.f / 512.f);
  float q = 0.f;
  #pragma unroll
  for (int j = 0; j < 8; ++j) q += (f[j] - mu) * (f[j] - mu);
  #pragma unroll
  for (int t = 1; t < 64; t <<= 1) q += __shfl_xor(q, t, 64);
  float rstd = rsqrtf(q * (1.f / 512.f) + 1e-5f);

  float4 g0 = *(const float4*)(g + lane * 8);
  float4 g1 = *(const float4*)(g + lane * 8 + 4);
  float4 b0 = *(const float4*)(be + lane * 8);
  float4 b1 = *(const float4*)(be + lane * 8 + 4);
  float y[8];
  y[0] = (f[0] - mu) * rstd * g0.x + b0.x; y[1] = (f[1] - mu) * rstd * g0.y + b0.y;
  y[2] = (f[2] - mu) * rstd * g0.z + b0.z; y[3] = (f[3] - mu) * rstd * g0.w + b0.w;
  y[4] = (f[4] - mu) * rstd * g1.x + b1.x; y[5] = (f[5] - mu) * rstd * g1.y + b1.y;
  y[6] = (f[6] - mu) * rstd * g1.z + b1.z; y[7] = (f[7] - mu) * rstd * g1.w + b1.w;
  if (OUTF32) {
    float4 o0 = {y[0], y[1], y[2], y[3]}, o1 = {y[4], y[5], y[6], y[7]};
    *(float4*)(Yf + (size_t)row * 512 + lane * 8) = o0;
    *(float4*)(Yf + (size_t)row * 512 + lane * 8 + 4) = o1;
  } else {
    uint4 u;
    u.x = pkbf(y[0], y[1]); u.y = pkbf(y[2], y[3]);
    u.z = pkbf(y[4], y[5]); u.w = pkbf(y[6], y[7]);
    *(uint4*)(Yb + (size_t)row * 512 + lane * 8) = u;
  }
}

// ---------------------------------------------------------------- launch
extern "C" void kernel_launch(void* const* d_in, const int* in_sizes, int n_in,
                              void* d_out, int out_size, void* d_ws, size_t ws_size,
                              hipStream_t stream) {
  const float* q_in = (const float*)d_in[0];
  const float* k_in = (const float*)d_in[1];
  const float* v_in = (const float*)d_in[2];
  const float* Wq = (const float*)d_in[3];  const float* bq = (const float*)d_in[4];
  const float* Wk = (const float*)d_in[5];  const float* bk = (const float*)d_in[6];
  const float* Wv = (const float*)d_in[7];  const float* bv = (const float*)d_in[8];
  const float* Wo = (const float*)d_in[9];  const float* bo = (const float*)d_in[10];
  const float* Wh = (const float*)d_in[11]; const float* bh = (const float*)d_in[12];
  const float* W2 = (const float*)d_in[13]; const float* b2 = (const float*)d_in[14];
  const float* g1 = (const float*)d_in[15]; const float* be1 = (const float*)d_in[16];
  const float* g2 = (const float*)d_in[17]; const float* be2 = (const float*)d_in[18];

  char* ws = (char*)d_ws;
  const size_t MD2 = (size_t)MTOT * 512 * 2;   // 8 MB bf16 buffer
  const size_t W1  = (size_t)512 * 512 * 2;
  unsigned short* qb_  = (unsigned short*)(ws);
  unsigned short* kb_  = (unsigned short*)(ws + MD2);
  unsigned short* vb_  = (unsigned short*)(ws + 2 * MD2);
  unsigned short* Qp   = (unsigned short*)(ws + 3 * MD2);
  unsigned short* Kp   = (unsigned short*)(ws + 4 * MD2);
  unsigned short* Vt   = (unsigned short*)(ws + 5 * MD2);
  unsigned short* Wt   = (unsigned short*)(ws + 6 * MD2);  // 6 matrices
  // aliases (consumer finished before producer writes):
  unsigned short* attn = vb_;   // vb last read by qkv gemm
  unsigned short* hy   = kb_;   // kb last read by qkv gemm
  unsigned short* ln1b = qb_;   // qb last read by qkv gemm
  unsigned short* f1   = Qp;    // Qp last read by attn
  unsigned short* y2   = Kp;    // Kp last read by attn

  cast3_kernel<<<dim3(MTOT * 512 / 2048, 3), 256, 0, stream>>>(q_in, k_in, v_in, qb_, kb_, vb_);
  transpose6_kernel<<<dim3(16, 16, 6), 256, 0, stream>>>(Wq, Wk, Wv, Wo, Wh, W2, Wt);

  // fused QKV projections (z: 0=Q,1=K,2=V-transposed)
  gemm_qkv_kernel<<<dim3(MTOT / 64, 8, 3), 256, 0, stream>>>(
      qb_, kb_, vb_, Wt, bq, bk, bv, Qp, Kp, Vt);

  // attention
  attn_kernel<<<dim3(BATCH * NH, 32), 256, 0, stream>>>(Qp, Kp, Vt, attn);

  dim3 gg(MTOT / 64, 8);
  // hy = bf16(attn @ Wo + bo + q)
  gemm_kernel<EPI_RESF32><<<gg, 256, 0, stream>>>(attn, Wt + 3 * 512 * 512, bo, q_in, hy);
  lnb_kernel<0><<<MTOT / 4, 256, 0, stream>>>(hy, g1, be1, nullptr, ln1b);
  // f1 = leaky(ln1 @ Wh + bh)
  gemm_kernel<EPI_LRELU><<<gg, 256, 0, stream>>>(ln1b, Wt + 4 * 512 * 512, bh, nullptr, f1);
  // y2 = bf16(f1 @ W2 + b2 + ln1)
  gemm_kernel<EPI_RESB16><<<gg, 256, 0, stream>>>(f1, Wt + 5 * 512 * 512, b2, ln1b, y2);
  lnb_kernel<1><<<MTOT / 4, 256, 0, stream>>>(y2, g2, be2, (float*)d_out, nullptr);
}

// Round 8
// 254.606 us; speedup vs baseline: 1.1665x; 1.1665x over previous
//
#include <hip/hip_runtime.h>
#include <math.h>

#define DIN   512
#define TSEQ  2048
#define BATCH 4
#define NH    8
#define DHEAD 64
#define MTOT  8192   // BATCH*TSEQ

typedef __attribute__((ext_vector_type(8))) __bf16 bf16x8;
typedef __attribute__((ext_vector_type(8))) short  s16x8;
typedef __attribute__((ext_vector_type(4))) float  f32x4;

__device__ __forceinline__ unsigned short f2b(float f) {
  union { float f; unsigned int u; } c; c.f = f;
  unsigned int r = (c.u + 0x7fffu + ((c.u >> 16) & 1u)) >> 16;
  return (unsigned short)r;
}

__device__ __forceinline__ float b2f(unsigned short u) {
  union { unsigned int i; float f; } c; c.i = (unsigned int)u << 16; return c.f;
}

__device__ __forceinline__ unsigned int pkbf(float a, float b) {
  union { __bf16 h[2]; unsigned int u; } c;
  c.h[0] = (__bf16)a; c.h[1] = (__bf16)b; return c.u;
}

__device__ __forceinline__ f32x4 mfma16(bf16x8 a, bf16x8 b, f32x4 c) {
  return __builtin_amdgcn_mfma_f32_16x16x32_bf16(a, b, c, 0, 0, 0);
}

// async global->LDS, 16B per lane; LDS dest = wave-uniform base + lane*16.
__device__ __forceinline__ void gload16(const void* gsrc, void* ldsbase) {
  __builtin_amdgcn_global_load_lds(
      (const __attribute__((address_space(1))) unsigned int*)gsrc,
      (__attribute__((address_space(3))) unsigned int*)(unsigned int)(unsigned long long)ldsbase,
      16, 0, 0);
}

#define WAITV(N) asm volatile("s_waitcnt vmcnt(" #N ")" ::: "memory")
#define VMCNT0_BARRIER() do { \
    asm volatile("s_waitcnt vmcnt(0)" ::: "memory"); \
    __builtin_amdgcn_s_barrier(); } while (0)

// ---------------------------------------------------------------- cast f32->bf16 (3 tensors)
__global__ __launch_bounds__(256) void cast3_kernel(const float* __restrict__ q,
                                                    const float* __restrict__ k,
                                                    const float* __restrict__ v,
                                                    unsigned short* __restrict__ oq,
                                                    unsigned short* __restrict__ ok,
                                                    unsigned short* __restrict__ ov) {
  const float* in = blockIdx.y == 0 ? q : blockIdx.y == 1 ? k : v;
  unsigned short* out = blockIdx.y == 0 ? oq : blockIdx.y == 1 ? ok : ov;
  int i = (blockIdx.x * 256 + threadIdx.x) * 8;
  float4 a = *(const float4*)(in + i);
  float4 b = *(const float4*)(in + i + 4);
  ushort4 u0, u1;
  u0.x = f2b(a.x); u0.y = f2b(a.y); u0.z = f2b(a.z); u0.w = f2b(a.w);
  u1.x = f2b(b.x); u1.y = f2b(b.y); u1.z = f2b(b.z); u1.w = f2b(b.w);
  *(ushort4*)(out + i) = u0;
  *(ushort4*)(out + i + 4) = u1;
}

// ---------------------------- 6x W [K][N] f32 -> Wt [N][K] bf16 (one launch)
__global__ __launch_bounds__(256) void transpose6_kernel(const float* __restrict__ w0,
                                                         const float* __restrict__ w1,
                                                         const float* __restrict__ w2,
                                                         const float* __restrict__ w3,
                                                         const float* __restrict__ w4,
                                                         const float* __restrict__ w5,
                                                         unsigned short* __restrict__ Wt) {
  const float* W;
  switch (blockIdx.z) {
    case 0: W = w0; break; case 1: W = w1; break; case 2: W = w2; break;
    case 3: W = w3; break; case 4: W = w4; break; default: W = w5; break;
  }
  unsigned short* dst = Wt + (size_t)blockIdx.z * 512 * 512;
  __shared__ float tile[32][33];
  int bx = blockIdx.x * 32, by = blockIdx.y * 32;
  int tx = threadIdx.x & 31, ty = threadIdx.x >> 5;
  #pragma unroll
  for (int yy = ty; yy < 32; yy += 8)
    tile[yy][tx] = W[(size_t)(by + yy) * DIN + bx + tx];
  __syncthreads();
  #pragma unroll
  for (int yy = ty; yy < 32; yy += 8)
    dst[(size_t)(bx + yy) * DIN + by + tx] = f2b(tile[tx][yy]);
}

// ---------------------------------------------------------------- GEMM core (weight-stationary)
// Block: BM=64 x BN=64, K=512. B panel [64][512] staged ONCE in LDS (64KB,
// chunk-XOR swizzled), one barrier total. Each of 4 waves owns 16 A-rows with
// a private 4-deep [16][32] staging ring -> K-loop has NO barriers; counted
// vmcnt(3) only. All LDS reads <=2-way bank aliasing (free, m136).
__device__ __forceinline__ void gemm_core_ws(const unsigned short* __restrict__ A,
                                             const unsigned short* __restrict__ Bt,
                                             int m0, int n0,
                                             unsigned short* __restrict__ Bls,   // [64*512]
                                             unsigned short* __restrict__ Alsw,  // wave's [4][512]
                                             f32x4* __restrict__ acc) {          // [4]
  const int tid = threadIdx.x, lane = tid & 63, w = tid >> 6;
  const int l = lane & 15, g = lane >> 4;

  // B panel: 16 rows/wave, one 1KB instr per row; source chunk pre-swizzled.
  #pragma unroll
  for (int i = 0; i < 16; ++i) {
    int row = w * 16 + i;
    gload16(Bt + (size_t)(n0 + row) * 512 + ((lane ^ (row & 7)) * 8),
            Bls + row * 512);
  }

  // A stage: instr covers 16 rows x 32 elems; chunk-swizzle within 4-chunk row.
  const int ar = lane >> 2;   // row 0..15
  const int ac = lane & 3;    // chunk 0..3
  const int asrc = (ac ^ ((ar >> 1) & 3)) * 8;
  #define ASTAGE(buf, t) \
    gload16(A + (size_t)(m0 + w * 16 + ar) * 512 + (t) * 32 + asrc, Alsw + (buf) * 512)

  ASTAGE(0, 0); ASTAGE(1, 1); ASTAGE(2, 2);
  WAITV(2);                        // B panel + A0 complete
  __builtin_amdgcn_s_barrier();    // B visible to all waves (the only barrier)

  const int aoff = l * 32 + (g ^ ((l >> 1) & 3)) * 8;
  #pragma unroll
  for (int t = 0; t < 16; ++t) {
    if (t + 3 < 16) ASTAGE((t + 3) & 3, t + 3);
    if (t < 13) { WAITV(3); } else if (t == 13) { WAITV(2); }
    else if (t == 14) { WAITV(1); } else { WAITV(0); }
    bf16x8 af = *(const bf16x8*)(Alsw + (t & 3) * 512 + aoff);
    #pragma unroll
    for (int n = 0; n < 4; ++n) {
      int row = n * 16 + l;
      int ch = (t * 4 + g) ^ (l & 7);
      bf16x8 bf = *(const bf16x8*)(Bls + row * 512 + ch * 8);
      acc[n] = mfma16(af, bf, acc[n]);
    }
  }
  #undef ASTAGE
}

enum { EPI_BF16 = 0, EPI_VT = 1, EPI_RESF32 = 2, EPI_RESB16 = 3, EPI_LRELU = 4 };

template <int EPI>
__global__ __launch_bounds__(256) void gemm_kernel(const unsigned short* __restrict__ A,
                                                   const unsigned short* __restrict__ Bt,
                                                   const float* __restrict__ bias,
                                                   const void* __restrict__ res,
                                                   unsigned short* __restrict__ out) {
  __shared__ unsigned short Bls[64 * 512];
  __shared__ unsigned short Als[4][4][512];
  const int lane = threadIdx.x & 63, w = threadIdx.x >> 6;
  const int l = lane & 15, g = lane >> 4;
  const int m0 = blockIdx.x * 64, n0 = blockIdx.y * 64;
  f32x4 acc[4] = {};
  gemm_core_ws(A, Bt, m0, n0, Bls, &Als[w][0][0], acc);

  int grb = m0 + w * 16 + g * 4;
  #pragma unroll
  for (int n = 0; n < 4; ++n) {
    int gc = n0 + n * 16 + l;
    float bv = bias[gc];
    #pragma unroll
    for (int r = 0; r < 4; ++r) {
      int gr = grb + r;
      float v = acc[n][r] + bv;
      if (EPI == EPI_RESF32) v += ((const float*)res)[(size_t)gr * 512 + gc];
      if (EPI == EPI_RESB16) v += b2f(((const unsigned short*)res)[(size_t)gr * 512 + gc]);
      if (EPI == EPI_LRELU)  v = v > 0.f ? v : 0.01f * v;
      if (EPI == EPI_VT) {   // Vt[(b*512+gc)][t]
        int b = gr >> 11, t = gr & 2047;
        out[((size_t)(b * 512 + gc) << 11) + t] = f2b(v);
      } else {
        out[(size_t)gr * 512 + gc] = f2b(v);
      }
    }
  }
}

// QKV fused (grid.z selects projection); z=2 writes transposed V.
__global__ __launch_bounds__(256) void gemm_qkv_kernel(const unsigned short* __restrict__ qb,
                                                       const unsigned short* __restrict__ kb,
                                                       const unsigned short* __restrict__ vb,
                                                       const unsigned short* __restrict__ Wt,
                                                       const float* __restrict__ bq,
                                                       const float* __restrict__ bk,
                                                       const float* __restrict__ bv,
                                                       unsigned short* __restrict__ Qp,
                                                       unsigned short* __restrict__ Kp,
                                                       unsigned short* __restrict__ Vt) {
  __shared__ unsigned short Bls[64 * 512];
  __shared__ unsigned short Als[4][4][512];
  const int z = blockIdx.z;
  const unsigned short* A = z == 0 ? qb : z == 1 ? kb : vb;
  const unsigned short* B = Wt + (size_t)z * 512 * 512;
  const float* bias = z == 0 ? bq : z == 1 ? bk : bv;
  const int lane = threadIdx.x & 63, w = threadIdx.x >> 6;
  const int l = lane & 15, g = lane >> 4;
  const int m0 = blockIdx.x * 64, n0 = blockIdx.y * 64;
  f32x4 acc[4] = {};
  gemm_core_ws(A, B, m0, n0, Bls, &Als[w][0][0], acc);

  int grb = m0 + w * 16 + g * 4;
  #pragma unroll
  for (int n = 0; n < 4; ++n) {
    int gc = n0 + n * 16 + l;
    float bvl = bias[gc];
    #pragma unroll
    for (int r = 0; r < 4; ++r) {
      int gr = grb + r;
      float v = acc[n][r] + bvl;
      if (z == 0) {
        Qp[(size_t)gr * 512 + gc] = f2b(v);
      } else if (z == 1) {
        Kp[(size_t)gr * 512 + gc] = f2b(v);
      } else {  // transposed: Vt[(b*512+gc)][t]
        int b = gr >> 11, t = gr & 2047;
        Vt[((size_t)(b * 512 + gc) << 11) + t] = f2b(v);
      }
    }
  }
}

// ---------------------------------------------------------------- flash attention (R6 structure)
// Grid (bh=32, qt=32), K and V staged in LDS via global_load_lds (swizzled,
// 2-buf); swapped QK^T; defer-rescale; row sums via ones-MFMA.
__global__ __launch_bounds__(256) void attn_kernel(const unsigned short* __restrict__ Q,
                                                   const unsigned short* __restrict__ K,
                                                   const unsigned short* __restrict__ Vt,
                                                   unsigned short* __restrict__ O) {
  __shared__ unsigned short Kls[2][64 * 64];
  __shared__ unsigned short Vls[2][64 * 64];
  __shared__ unsigned short Pls[4][16 * 64];
  const int tid = threadIdx.x, lane = tid & 63, w = tid >> 6;
  const int l = lane & 15, g = lane >> 4;
  const int bh = blockIdx.x;           // id%8 = bh%8 -> XCD locality
  const int qt = (int)gridDim.y - 1 - (int)blockIdx.y;  // longest first
  const int b = bh >> 3, h = bh & 7;
  const int sx = (l & 7) * 8;          // read-side swizzle (elems)
  const float SC2 = 0.125f * 1.44269504088896340736f;
  const float THR = 64.f;              // raw-score defer threshold (~e^8 bound)

  const int r8 = lane >> 3;
  const int sce = ((lane & 7) ^ r8) * 8;  // inverse-swizzled source col (elems)

  #define STAGEKV(buf, kv0) do { \
      _Pragma("unroll") \
      for (int i_ = 0; i_ < 2; ++i_) { \
        int ii_ = w * 2 + i_; \
        int row_ = ii_ * 8 + r8; \
        gload16(K  + (size_t)(b * 2048 + (kv0) + row_) * 512 + h * 64 + sce, &Kls[buf][ii_ * 512]); \
        gload16(Vt + (size_t)(b * 512 + h * 64 + row_) * 2048 + (kv0) + sce, &Vls[buf][ii_ * 512]); \
      } } while (0)

  const int q0 = qt * 64 + w * 16;
  bf16x8 qf[2];
  #pragma unroll
  for (int kf = 0; kf < 2; ++kf)
    qf[kf] = *(const bf16x8*)(Q + (size_t)(b * 2048 + q0 + l) * 512 + h * 64 + kf * 32 + g * 8);

  bf16x8 vones;
  #pragma unroll
  for (int i = 0; i < 8; ++i) vones[i] = (__bf16)1.0f;

  float mrun = -1e30f;
  f32x4 o[4] = {};
  f32x4 os = {0.f, 0.f, 0.f, 0.f};

  STAGEKV(0, 0);
  VMCNT0_BARRIER();

  for (int s = 0; s <= qt; ++s) {
    int cur = s & 1;
    int kv0 = s * 64;
    if (s < qt) STAGEKV(cur ^ 1, kv0 + 64);

    // S^T (raw): lane holds S[q=q0+l][kv = kv0 + t*16 + g*4 + r]
    f32x4 st[4];
    #pragma unroll
    for (int t = 0; t < 4; ++t) {
      st[t] = f32x4{0.f, 0.f, 0.f, 0.f};
      #pragma unroll
      for (int kf = 0; kf < 2; ++kf) {
        bf16x8 kfr = *(const bf16x8*)(&Kls[cur][(t * 16 + l) * 64 + ((kf * 32 + g * 8) ^ sx)]);
        st[t] = mfma16(kfr, qf[kf], st[t]);
      }
    }
    if (s == qt) {   // only the diagonal step masks
      const int qrow = q0 + l;
      #pragma unroll
      for (int t = 0; t < 4; ++t)
        #pragma unroll
        for (int r = 0; r < 4; ++r)
          if (kv0 + t * 16 + g * 4 + r > qrow) st[t][r] = -1e30f;
    }

    float mx = fmaxf(
        fmaxf(fmaxf(fmaxf(st[0][0], st[0][1]), st[0][2]),
              fmaxf(fmaxf(st[0][3], st[1][0]), st[1][1])),
        fmaxf(fmaxf(fmaxf(st[1][2], st[1][3]), st[2][0]),
              fmaxf(fmaxf(st[2][1], st[2][2]), st[2][3])));
    mx = fmaxf(mx, fmaxf(fmaxf(st[3][0], st[3][1]), fmaxf(st[3][2], st[3][3])));
    mx = fmaxf(mx, __shfl_xor(mx, 16, 64));
    mx = fmaxf(mx, __shfl_xor(mx, 32, 64));

    if (!__all(mx <= mrun + THR)) {   // T13 defer-rescale
      float nm = fmaxf(mrun, mx);
      float alpha = exp2f((mrun - nm) * SC2);
      mrun = nm;
      #pragma unroll
      for (int r = 0; r < 4; ++r) {
        float ar = __shfl(alpha, g * 4 + r, 64);
        #pragma unroll
        for (int n = 0; n < 4; ++n) o[n][r] *= ar;
        os[r] *= ar;
      }
    }

    float mS = mrun * SC2;
    #pragma unroll
    for (int t = 0; t < 4; ++t)
      #pragma unroll
      for (int r = 0; r < 4; ++r)
        st[t][r] = exp2f(fmaf(st[t][r], SC2, -mS));

    // P pack -> swizzled per-wave LDS [16][64], then PV (+ ones for row sums)
    #pragma unroll
    for (int t = 0; t < 4; ++t) {
      uint2 u;
      u.x = pkbf(st[t][0], st[t][1]);
      u.y = pkbf(st[t][2], st[t][3]);
      *(uint2*)(&Pls[w][l * 64 + ((t * 16 + g * 4) ^ sx)]) = u;
    }
    #pragma unroll
    for (int kf = 0; kf < 2; ++kf) {
      bf16x8 pa = *(const bf16x8*)(&Pls[w][l * 64 + ((kf * 32 + g * 8) ^ sx)]);
      #pragma unroll
      for (int n = 0; n < 4; ++n) {
        bf16x8 vf = *(const bf16x8*)(&Vls[cur][(n * 16 + l) * 64 + ((kf * 32 + g * 8) ^ sx)]);
        o[n] = mfma16(pa, vf, o[n]);
      }
      os = mfma16(pa, vones, os);
    }

    VMCNT0_BARRIER();
  }

  #pragma unroll
  for (int r = 0; r < 4; ++r) {
    float lir = 1.f / os[r];
    #pragma unroll
    for (int n = 0; n < 4; ++n)
      O[(size_t)(b * 2048 + q0 + g * 4 + r) * 512 + h * 64 + n * 16 + l] =
          f2b(o[n][r] * lir);
  }
  #undef STAGEKV
}

// ---------------------------------------------------------------- LayerNorm (bf16 in)
template <int OUTF32>
__global__ __launch_bounds__(256) void lnb_kernel(const unsigned short* __restrict__ X,
                                                  const float* __restrict__ g,
                                                  const float* __restrict__ be,
                                                  float* __restrict__ Yf,
                                                  unsigned short* __restrict__ Yb) {
  int row = blockIdx.x * 4 + (threadIdx.x >> 6);
  int lane = threadIdx.x & 63;
  s16x8 v = *(const s16x8*)(X + (size_t)row * 512 + lane * 8);
  float f[8];
  #pragma unroll
  for (int j = 0; j < 8; ++j) f[j] = b2f((unsigned short)v[j]);
  float s = 0.f;
  #pragma unroll
  for (int j = 0; j < 8; ++j) s += f[j];
  #pragma unroll
  for (int t = 1; t < 64; t <<= 1) s += __shfl_xor(s, t, 64);
  float mu = s * (1.f / 512.f);
  float q = 0.f;
  #pragma unroll
  for (int j = 0; j < 8; ++j) q += (f[j] - mu) * (f[j] - mu);
  #pragma unroll
  for (int t = 1; t < 64; t <<= 1) q += __shfl_xor(q, t, 64);
  float rstd = rsqrtf(q * (1.f / 512.f) + 1e-5f);

  float4 g0 = *(const float4*)(g + lane * 8);
  float4 g1 = *(const float4*)(g + lane * 8 + 4);
  float4 b0 = *(const float4*)(be + lane * 8);
  float4 b1 = *(const float4*)(be + lane * 8 + 4);
  float y[8];
  y[0] = (f[0] - mu) * rstd * g0.x + b0.x; y[1] = (f[1] - mu) * rstd * g0.y + b0.y;
  y[2] = (f[2] - mu) * rstd * g0.z + b0.z; y[3] = (f[3] - mu) * rstd * g0.w + b0.w;
  y[4] = (f[4] - mu) * rstd * g1.x + b1.x; y[5] = (f[5] - mu) * rstd * g1.y + b1.y;
  y[6] = (f[6] - mu) * rstd * g1.z + b1.z; y[7] = (f[7] - mu) * rstd * g1.w + b1.w;
  if (OUTF32) {
    float4 o0 = {y[0], y[1], y[2], y[3]}, o1 = {y[4], y[5], y[6], y[7]};
    *(float4*)(Yf + (size_t)row * 512 + lane * 8) = o0;
    *(float4*)(Yf + (size_t)row * 512 + lane * 8 + 4) = o1;
  } else {
    uint4 u;
    u.x = pkbf(y[0], y[1]); u.y = pkbf(y[2], y[3]);
    u.z = pkbf(y[4], y[5]); u.w = pkbf(y[6], y[7]);
    *(uint4*)(Yb + (size_t)row * 512 + lane * 8) = u;
  }
}

// ---------------------------------------------------------------- launch
extern "C" void kernel_launch(void* const* d_in, const int* in_sizes, int n_in,
                              void* d_out, int out_size, void* d_ws, size_t ws_size,
                              hipStream_t stream) {
  const float* q_in = (const float*)d_in[0];
  const float* k_in = (const float*)d_in[1];
  const float* v_in = (const float*)d_in[2];
  const float* Wq = (const float*)d_in[3];  const float* bq = (const float*)d_in[4];
  const float* Wk = (const float*)d_in[5];  const float* bk = (const float*)d_in[6];
  const float* Wv = (const float*)d_in[7];  const float* bv = (const float*)d_in[8];
  const float* Wo = (const float*)d_in[9];  const float* bo = (const float*)d_in[10];
  const float* Wh = (const float*)d_in[11]; const float* bh = (const float*)d_in[12];
  const float* W2 = (const float*)d_in[13]; const float* b2 = (const float*)d_in[14];
  const float* g1 = (const float*)d_in[15]; const float* be1 = (const float*)d_in[16];
  const float* g2 = (const float*)d_in[17]; const float* be2 = (const float*)d_in[18];

  char* ws = (char*)d_ws;
  const size_t MD2 = (size_t)MTOT * 512 * 2;   // 8 MB bf16 buffer
  const size_t W1  = (size_t)512 * 512 * 2;
  unsigned short* qb_  = (unsigned short*)(ws);
  unsigned short* kb_  = (unsigned short*)(ws + MD2);
  unsigned short* vb_  = (unsigned short*)(ws + 2 * MD2);
  unsigned short* Qp   = (unsigned short*)(ws + 3 * MD2);
  unsigned short* Kp   = (unsigned short*)(ws + 4 * MD2);
  unsigned short* Vt   = (unsigned short*)(ws + 5 * MD2);
  unsigned short* Wt   = (unsigned short*)(ws + 6 * MD2);  // 6 matrices
  // aliases (consumer finished before producer writes):
  unsigned short* attn = vb_;   // vb last read by qkv gemm
  unsigned short* hy   = kb_;   // kb last read by qkv gemm
  unsigned short* ln1b = qb_;   // qb last read by qkv gemm
  unsigned short* f1   = Qp;    // Qp last read by attn
  unsigned short* y2   = Kp;    // Kp last read by attn

  cast3_kernel<<<dim3(MTOT * 512 / 2048, 3), 256, 0, stream>>>(q_in, k_in, v_in, qb_, kb_, vb_);
  transpose6_kernel<<<dim3(16, 16, 6), 256, 0, stream>>>(Wq, Wk, Wv, Wo, Wh, W2, Wt);

  // fused QKV projections (z: 0=Q,1=K,2=V-transposed)
  gemm_qkv_kernel<<<dim3(MTOT / 64, 8, 3), 256, 0, stream>>>(
      qb_, kb_, vb_, Wt, bq, bk, bv, Qp, Kp, Vt);

  // attention
  attn_kernel<<<dim3(BATCH * NH, 32), 256, 0, stream>>>(Qp, Kp, Vt, attn);

  dim3 gg(MTOT / 64, 8);
  // hy = bf16(attn @ Wo + bo + q)
  gemm_kernel<EPI_RESF32><<<gg, 256, 0, stream>>>(attn, Wt + 3 * 512 * 512, bo, q_in, hy);
  lnb_kernel<0><<<MTOT / 4, 256, 0, stream>>>(hy, g1, be1, nullptr, ln1b);
  // f1 = leaky(ln1 @ Wh + bh)
  gemm_kernel<EPI_LRELU><<<gg, 256, 0, stream>>>(ln1b, Wt + 4 * 512 * 512, bh, nullptr, f1);
  // y2 = bf16(f1 @ W2 + b2 + ln1)
  gemm_kernel<EPI_RESB16><<<gg, 256, 0, stream>>>(f1, Wt + 5 * 512 * 512, b2, ln1b, y2);
  lnb_kernel<1><<<MTOT / 4, 256, 0, stream>>>(y2, g2, be2, (float*)d_out, nullptr);
}

// Round 9
// 248.473 us; speedup vs baseline: 1.1953x; 1.0247x over previous
//
#include <hip/hip_runtime.h>
#include <math.h>

#define DIN   512
#define TSEQ  2048
#define BATCH 4
#define NH    8
#define DHEAD 64
#define MTOT  8192   // BATCH*TSEQ

typedef __attribute__((ext_vector_type(8))) __bf16 bf16x8;
typedef __attribute__((ext_vector_type(8))) short  s16x8;
typedef __attribute__((ext_vector_type(4))) float  f32x4;

__device__ __forceinline__ unsigned short f2b(float f) {
  union { float f; unsigned int u; } c; c.f = f;
  unsigned int r = (c.u + 0x7fffu + ((c.u >> 16) & 1u)) >> 16;
  return (unsigned short)r;
}

__device__ __forceinline__ float b2f(unsigned short u) {
  union { unsigned int i; float f; } c; c.i = (unsigned int)u << 16; return c.f;
}

__device__ __forceinline__ unsigned int pkbf(float a, float b) {
  union { __bf16 h[2]; unsigned int u; } c;
  c.h[0] = (__bf16)a; c.h[1] = (__bf16)b; return c.u;
}

__device__ __forceinline__ f32x4 mfma16(bf16x8 a, bf16x8 b, f32x4 c) {
  return __builtin_amdgcn_mfma_f32_16x16x32_bf16(a, b, c, 0, 0, 0);
}

// async global->LDS, 16B per lane; LDS dest = wave-uniform base + lane*16.
__device__ __forceinline__ void gload16(const void* gsrc, void* ldsbase) {
  __builtin_amdgcn_global_load_lds(
      (const __attribute__((address_space(1))) unsigned int*)gsrc,
      (__attribute__((address_space(3))) unsigned int*)(unsigned int)(unsigned long long)ldsbase,
      16, 0, 0);
}

#define WAITV(N) asm volatile("s_waitcnt vmcnt(" #N ")" ::: "memory")
#define VMCNT0_BARRIER() do { \
    asm volatile("s_waitcnt vmcnt(0)" ::: "memory"); \
    __builtin_amdgcn_s_barrier(); } while (0)

// ---------------------------------------------------------------- cast f32->bf16 (3 tensors)
__global__ __launch_bounds__(256) void cast3_kernel(const float* __restrict__ q,
                                                    const float* __restrict__ k,
                                                    const float* __restrict__ v,
                                                    unsigned short* __restrict__ oq,
                                                    unsigned short* __restrict__ ok,
                                                    unsigned short* __restrict__ ov) {
  const float* in = blockIdx.y == 0 ? q : blockIdx.y == 1 ? k : v;
  unsigned short* out = blockIdx.y == 0 ? oq : blockIdx.y == 1 ? ok : ov;
  int i = (blockIdx.x * 256 + threadIdx.x) * 8;
  float4 a = *(const float4*)(in + i);
  float4 b = *(const float4*)(in + i + 4);
  ushort4 u0, u1;
  u0.x = f2b(a.x); u0.y = f2b(a.y); u0.z = f2b(a.z); u0.w = f2b(a.w);
  u1.x = f2b(b.x); u1.y = f2b(b.y); u1.z = f2b(b.z); u1.w = f2b(b.w);
  *(ushort4*)(out + i) = u0;
  *(ushort4*)(out + i + 4) = u1;
}

// ---------------------------- 6x W [K][N] f32 -> Wt [N][K] bf16 (one launch)
__global__ __launch_bounds__(256) void transpose6_kernel(const float* __restrict__ w0,
                                                         const float* __restrict__ w1,
                                                         const float* __restrict__ w2,
                                                         const float* __restrict__ w3,
                                                         const float* __restrict__ w4,
                                                         const float* __restrict__ w5,
                                                         unsigned short* __restrict__ Wt) {
  const float* W;
  switch (blockIdx.z) {
    case 0: W = w0; break; case 1: W = w1; break; case 2: W = w2; break;
    case 3: W = w3; break; case 4: W = w4; break; default: W = w5; break;
  }
  unsigned short* dst = Wt + (size_t)blockIdx.z * 512 * 512;
  __shared__ float tile[32][33];
  int bx = blockIdx.x * 32, by = blockIdx.y * 32;
  int tx = threadIdx.x & 31, ty = threadIdx.x >> 5;
  #pragma unroll
  for (int yy = ty; yy < 32; yy += 8)
    tile[yy][tx] = W[(size_t)(by + yy) * DIN + bx + tx];
  __syncthreads();
  #pragma unroll
  for (int yy = ty; yy < 32; yy += 8)
    dst[(size_t)(bx + yy) * DIN + by + tx] = f2b(tile[tx][yy]);
}

// ---------------------------------------------------------------- GEMM core
// BM=64, BN=64, BK=32, 16 K-steps; 4 waves (2x2), wave tile 32x32, acc 2x2.
// 4-buffer LDS (32KB -> 4 blk/CU), depth-3 prefetch, counted vmcnt:
// per step: [WAITV(4) drains tile t] [barrier] [stage t+3] [compute t].
// BK=32 row stride (64B) is bank-conflict-free for b128 frag reads.
__device__ __forceinline__ void gemm_core(const unsigned short* __restrict__ A,
                                          const unsigned short* __restrict__ Bt,
                                          int m0, int n0,
                                          unsigned short (*Als)[64 * 32],
                                          unsigned short (*Bls)[64 * 32],
                                          f32x4 (*acc)[2]) {
  const int tid = threadIdx.x, lane = tid & 63, w = tid >> 6;
  const int wr = w >> 1, wc = w & 1;
  const int l = lane & 15, g = lane >> 4;
  const int srow = lane >> 2;        // 0..15 rows within one 1KB instr
  const int sce  = (lane & 3) * 8;   // col elems within 32-elem row

  // per wave per stage: 1 A-instr + 1 B-instr (each 1KB = 16 rows x 32 elems)
  #define GSTAGE(buf, k0) do { \
      gload16(A  + (size_t)(m0 + w * 16 + srow) * 512 + (k0) + sce, &Als[buf][w * 512]); \
      gload16(Bt + (size_t)(n0 + w * 16 + srow) * 512 + (k0) + sce, &Bls[buf][w * 512]); \
    } while (0)

  GSTAGE(0, 0);
  GSTAGE(1, 32);
  GSTAGE(2, 64);
  #pragma unroll
  for (int t = 0; t < 16; ++t) {
    if (t < 14) { WAITV(4); } else if (t == 14) { WAITV(2); } else { WAITV(0); }
    __builtin_amdgcn_s_barrier();
    if (t + 3 < 16) GSTAGE((t + 3) & 3, (t + 3) * 32);
    const int cur = t & 3;
    bf16x8 af[2], bf[2];
    #pragma unroll
    for (int m = 0; m < 2; ++m)
      af[m] = *(const bf16x8*)(&Als[cur][(wr * 32 + m * 16 + l) * 32 + g * 8]);
    #pragma unroll
    for (int n = 0; n < 2; ++n)
      bf[n] = *(const bf16x8*)(&Bls[cur][(wc * 32 + n * 16 + l) * 32 + g * 8]);
    #pragma unroll
    for (int m = 0; m < 2; ++m)
      #pragma unroll
      for (int n = 0; n < 2; ++n)
        acc[m][n] = mfma16(af[m], bf[n], acc[m][n]);
  }
  #undef GSTAGE
}

enum { EPI_BF16 = 0, EPI_VT = 1, EPI_RESF32 = 2, EPI_RESB16 = 3, EPI_LRELU = 4 };

template <int EPI>
__global__ __launch_bounds__(256) void gemm_kernel(const unsigned short* __restrict__ A,
                                                   const unsigned short* __restrict__ Bt,
                                                   const float* __restrict__ bias,
                                                   const void* __restrict__ res,
                                                   unsigned short* __restrict__ out) {
  __shared__ unsigned short Als[4][64 * 32];
  __shared__ unsigned short Bls[4][64 * 32];
  const int lane = threadIdx.x & 63, w = threadIdx.x >> 6;
  const int wr = w >> 1, wc = w & 1;
  const int l = lane & 15, g = lane >> 4;
  const int m0 = blockIdx.x * 64, n0 = blockIdx.y * 64;
  f32x4 acc[2][2] = {};
  gemm_core(A, Bt, m0, n0, Als, Bls, acc);

  #pragma unroll
  for (int m = 0; m < 2; ++m) {
    int grb = m0 + wr * 32 + m * 16 + g * 4;
    #pragma unroll
    for (int n = 0; n < 2; ++n) {
      int gc = n0 + wc * 32 + n * 16 + l;
      float bv = bias[gc];
      #pragma unroll
      for (int r = 0; r < 4; ++r) {
        int gr = grb + r;
        float v = acc[m][n][r] + bv;
        if (EPI == EPI_RESF32) v += ((const float*)res)[(size_t)gr * 512 + gc];
        if (EPI == EPI_RESB16) v += b2f(((const unsigned short*)res)[(size_t)gr * 512 + gc]);
        if (EPI == EPI_LRELU)  v = v > 0.f ? v : 0.01f * v;
        if (EPI == EPI_VT) {   // Vt[(b*512+gc)][t]
          int b = gr >> 11, t = gr & 2047;
          out[((size_t)(b * 512 + gc) << 11) + t] = f2b(v);
        } else {
          out[(size_t)gr * 512 + gc] = f2b(v);
        }
      }
    }
  }
}

// QKV fused (grid.z selects projection); z=2 writes transposed V.
__global__ __launch_bounds__(256) void gemm_qkv_kernel(const unsigned short* __restrict__ qb,
                                                       const unsigned short* __restrict__ kb,
                                                       const unsigned short* __restrict__ vb,
                                                       const unsigned short* __restrict__ Wt,
                                                       const float* __restrict__ bq,
                                                       const float* __restrict__ bk,
                                                       const float* __restrict__ bv,
                                                       unsigned short* __restrict__ Qp,
                                                       unsigned short* __restrict__ Kp,
                                                       unsigned short* __restrict__ Vt) {
  __shared__ unsigned short Als[4][64 * 32];
  __shared__ unsigned short Bls[4][64 * 32];
  const int z = blockIdx.z;
  const unsigned short* A = z == 0 ? qb : z == 1 ? kb : vb;
  const unsigned short* B = Wt + (size_t)z * 512 * 512;
  const float* bias = z == 0 ? bq : z == 1 ? bk : bv;
  const int lane = threadIdx.x & 63, w = threadIdx.x >> 6;
  const int wr = w >> 1, wc = w & 1;
  const int l = lane & 15, g = lane >> 4;
  const int m0 = blockIdx.x * 64, n0 = blockIdx.y * 64;
  f32x4 acc[2][2] = {};
  gemm_core(A, B, m0, n0, Als, Bls, acc);

  #pragma unroll
  for (int m = 0; m < 2; ++m) {
    int grb = m0 + wr * 32 + m * 16 + g * 4;
    #pragma unroll
    for (int n = 0; n < 2; ++n) {
      int gc = n0 + wc * 32 + n * 16 + l;
      float bvl = bias[gc];
      #pragma unroll
      for (int r = 0; r < 4; ++r) {
        int gr = grb + r;
        float v = acc[m][n][r] + bvl;
        if (z == 0) {
          Qp[(size_t)gr * 512 + gc] = f2b(v);
        } else if (z == 1) {
          Kp[(size_t)gr * 512 + gc] = f2b(v);
        } else {  // transposed: Vt[(b*512+gc)][t]
          int b = gr >> 11, t = gr & 2047;
          Vt[((size_t)(b * 512 + gc) << 11) + t] = f2b(v);
        }
      }
    }
  }
}

// ---------------------------------------------------------------- flash attention (R8 control)
// Grid (bh=32, qt=32), K and V staged in LDS via global_load_lds (swizzled,
// 2-buf); swapped QK^T; defer-rescale; row sums via ones-MFMA.
__global__ __launch_bounds__(256) void attn_kernel(const unsigned short* __restrict__ Q,
                                                   const unsigned short* __restrict__ K,
                                                   const unsigned short* __restrict__ Vt,
                                                   unsigned short* __restrict__ O) {
  __shared__ unsigned short Kls[2][64 * 64];
  __shared__ unsigned short Vls[2][64 * 64];
  __shared__ unsigned short Pls[4][16 * 64];
  const int tid = threadIdx.x, lane = tid & 63, w = tid >> 6;
  const int l = lane & 15, g = lane >> 4;
  const int bh = blockIdx.x;           // id%8 = bh%8 -> XCD locality
  const int qt = (int)gridDim.y - 1 - (int)blockIdx.y;  // longest first
  const int b = bh >> 3, h = bh & 7;
  const int sx = (l & 7) * 8;          // read-side swizzle (elems)
  const float SC2 = 0.125f * 1.44269504088896340736f;
  const float THR = 64.f;              // raw-score defer threshold (~e^8 bound)

  const int r8 = lane >> 3;
  const int sce = ((lane & 7) ^ r8) * 8;  // inverse-swizzled source col (elems)

  #define STAGEKV(buf, kv0) do { \
      _Pragma("unroll") \
      for (int i_ = 0; i_ < 2; ++i_) { \
        int ii_ = w * 2 + i_; \
        int row_ = ii_ * 8 + r8; \
        gload16(K  + (size_t)(b * 2048 + (kv0) + row_) * 512 + h * 64 + sce, &Kls[buf][ii_ * 512]); \
        gload16(Vt + (size_t)(b * 512 + h * 64 + row_) * 2048 + (kv0) + sce, &Vls[buf][ii_ * 512]); \
      } } while (0)

  const int q0 = qt * 64 + w * 16;
  bf16x8 qf[2];
  #pragma unroll
  for (int kf = 0; kf < 2; ++kf)
    qf[kf] = *(const bf16x8*)(Q + (size_t)(b * 2048 + q0 + l) * 512 + h * 64 + kf * 32 + g * 8);

  bf16x8 vones;
  #pragma unroll
  for (int i = 0; i < 8; ++i) vones[i] = (__bf16)1.0f;

  float mrun = -1e30f;
  f32x4 o[4] = {};
  f32x4 os = {0.f, 0.f, 0.f, 0.f};

  STAGEKV(0, 0);
  VMCNT0_BARRIER();

  for (int s = 0; s <= qt; ++s) {
    int cur = s & 1;
    int kv0 = s * 64;
    if (s < qt) STAGEKV(cur ^ 1, kv0 + 64);

    // S^T (raw): lane holds S[q=q0+l][kv = kv0 + t*16 + g*4 + r]
    f32x4 st[4];
    #pragma unroll
    for (int t = 0; t < 4; ++t) {
      st[t] = f32x4{0.f, 0.f, 0.f, 0.f};
      #pragma unroll
      for (int kf = 0; kf < 2; ++kf) {
        bf16x8 kfr = *(const bf16x8*)(&Kls[cur][(t * 16 + l) * 64 + ((kf * 32 + g * 8) ^ sx)]);
        st[t] = mfma16(kfr, qf[kf], st[t]);
      }
    }
    if (s == qt) {   // only the diagonal step masks
      const int qrow = q0 + l;
      #pragma unroll
      for (int t = 0; t < 4; ++t)
        #pragma unroll
        for (int r = 0; r < 4; ++r)
          if (kv0 + t * 16 + g * 4 + r > qrow) st[t][r] = -1e30f;
    }

    float mx = fmaxf(
        fmaxf(fmaxf(fmaxf(st[0][0], st[0][1]), st[0][2]),
              fmaxf(fmaxf(st[0][3], st[1][0]), st[1][1])),
        fmaxf(fmaxf(fmaxf(st[1][2], st[1][3]), st[2][0]),
              fmaxf(fmaxf(st[2][1], st[2][2]), st[2][3])));
    mx = fmaxf(mx, fmaxf(fmaxf(st[3][0], st[3][1]), fmaxf(st[3][2], st[3][3])));
    mx = fmaxf(mx, __shfl_xor(mx, 16, 64));
    mx = fmaxf(mx, __shfl_xor(mx, 32, 64));

    if (!__all(mx <= mrun + THR)) {   // T13 defer-rescale
      float nm = fmaxf(mrun, mx);
      float alpha = exp2f((mrun - nm) * SC2);
      mrun = nm;
      #pragma unroll
      for (int r = 0; r < 4; ++r) {
        float ar = __shfl(alpha, g * 4 + r, 64);
        #pragma unroll
        for (int n = 0; n < 4; ++n) o[n][r] *= ar;
        os[r] *= ar;
      }
    }

    float mS = mrun * SC2;
    #pragma unroll
    for (int t = 0; t < 4; ++t)
      #pragma unroll
      for (int r = 0; r < 4; ++r)
        st[t][r] = exp2f(fmaf(st[t][r], SC2, -mS));

    // P pack -> swizzled per-wave LDS [16][64], then PV (+ ones for row sums)
    #pragma unroll
    for (int t = 0; t < 4; ++t) {
      uint2 u;
      u.x = pkbf(st[t][0], st[t][1]);
      u.y = pkbf(st[t][2], st[t][3]);
      *(uint2*)(&Pls[w][l * 64 + ((t * 16 + g * 4) ^ sx)]) = u;
    }
    #pragma unroll
    for (int kf = 0; kf < 2; ++kf) {
      bf16x8 pa = *(const bf16x8*)(&Pls[w][l * 64 + ((kf * 32 + g * 8) ^ sx)]);
      #pragma unroll
      for (int n = 0; n < 4; ++n) {
        bf16x8 vf = *(const bf16x8*)(&Vls[cur][(n * 16 + l) * 64 + ((kf * 32 + g * 8) ^ sx)]);
        o[n] = mfma16(pa, vf, o[n]);
      }
      os = mfma16(pa, vones, os);
    }

    VMCNT0_BARRIER();
  }

  #pragma unroll
  for (int r = 0; r < 4; ++r) {
    float lir = 1.f / os[r];
    #pragma unroll
    for (int n = 0; n < 4; ++n)
      O[(size_t)(b * 2048 + q0 + g * 4 + r) * 512 + h * 64 + n * 16 + l] =
          f2b(o[n][r] * lir);
  }
  #undef STAGEKV
}

// ---------------------------------------------------------------- LayerNorm (bf16 in)
template <int OUTF32>
__global__ __launch_bounds__(256) void lnb_kernel(const unsigned short* __restrict__ X,
                                                  const float* __restrict__ g,
                                                  const float* __restrict__ be,
                                                  float* __restrict__ Yf,
                                                  unsigned short* __restrict__ Yb) {
  int row = blockIdx.x * 4 + (threadIdx.x >> 6);
  int lane = threadIdx.x & 63;
  s16x8 v = *(const s16x8*)(X + (size_t)row * 512 + lane * 8);
  float f[8];
  #pragma unroll
  for (int j = 0; j < 8; ++j) f[j] = b2f((unsigned short)v[j]);
  float s = 0.f;
  #pragma unroll
  for (int j = 0; j < 8; ++j) s += f[j];
  #pragma unroll
  for (int t = 1; t < 64; t <<= 1) s += __shfl_xor(s, t, 64);
  float mu = s * (1.f / 512.f);
  float q = 0.f;
  #pragma unroll
  for (int j = 0; j < 8; ++j) q += (f[j] - mu) * (f[j] - mu);
  #pragma unroll
  for (int t = 1; t < 64; t <<= 1) q += __shfl_xor(q, t, 64);
  float rstd = rsqrtf(q * (1.f / 512.f) + 1e-5f);

  float4 g0 = *(const float4*)(g + lane * 8);
  float4 g1 = *(const float4*)(g + lane * 8 + 4);
  float4 b0 = *(const float4*)(be + lane * 8);
  float4 b1 = *(const float4*)(be + lane * 8 + 4);
  float y[8];
  y[0] = (f[0] - mu) * rstd * g0.x + b0.x; y[1] = (f[1] - mu) * rstd * g0.y + b0.y;
  y[2] = (f[2] - mu) * rstd * g0.z + b0.z; y[3] = (f[3] - mu) * rstd * g0.w + b0.w;
  y[4] = (f[4] - mu) * rstd * g1.x + b1.x; y[5] = (f[5] - mu) * rstd * g1.y + b1.y;
  y[6] = (f[6] - mu) * rstd * g1.z + b1.z; y[7] = (f[7] - mu) * rstd * g1.w + b1.w;
  if (OUTF32) {
    float4 o0 = {y[0], y[1], y[2], y[3]}, o1 = {y[4], y[5], y[6], y[7]};
    *(float4*)(Yf + (size_t)row * 512 + lane * 8) = o0;
    *(float4*)(Yf + (size_t)row * 512 + lane * 8 + 4) = o1;
  } else {
    uint4 u;
    u.x = pkbf(y[0], y[1]); u.y = pkbf(y[2], y[3]);
    u.z = pkbf(y[4], y[5]); u.w = pkbf(y[6], y[7]);
    *(uint4*)(Yb + (size_t)row * 512 + lane * 8) = u;
  }
}

// ---------------------------------------------------------------- launch
extern "C" void kernel_launch(void* const* d_in, const int* in_sizes, int n_in,
                              void* d_out, int out_size, void* d_ws, size_t ws_size,
                              hipStream_t stream) {
  const float* q_in = (const float*)d_in[0];
  const float* k_in = (const float*)d_in[1];
  const float* v_in = (const float*)d_in[2];
  const float* Wq = (const float*)d_in[3];  const float* bq = (const float*)d_in[4];
  const float* Wk = (const float*)d_in[5];  const float* bk = (const float*)d_in[6];
  const float* Wv = (const float*)d_in[7];  const float* bv = (const float*)d_in[8];
  const float* Wo = (const float*)d_in[9];  const float* bo = (const float*)d_in[10];
  const float* Wh = (const float*)d_in[11]; const float* bh = (const float*)d_in[12];
  const float* W2 = (const float*)d_in[13]; const float* b2 = (const float*)d_in[14];
  const float* g1 = (const float*)d_in[15]; const float* be1 = (const float*)d_in[16];
  const float* g2 = (const float*)d_in[17]; const float* be2 = (const float*)d_in[18];

  char* ws = (char*)d_ws;
  const size_t MD2 = (size_t)MTOT * 512 * 2;   // 8 MB bf16 buffer
  const size_t W1  = (size_t)512 * 512 * 2;
  unsigned short* qb_  = (unsigned short*)(ws);
  unsigned short* kb_  = (unsigned short*)(ws + MD2);
  unsigned short* vb_  = (unsigned short*)(ws + 2 * MD2);
  unsigned short* Qp   = (unsigned short*)(ws + 3 * MD2);
  unsigned short* Kp   = (unsigned short*)(ws + 4 * MD2);
  unsigned short* Vt   = (unsigned short*)(ws + 5 * MD2);
  unsigned short* Wt   = (unsigned short*)(ws + 6 * MD2);  // 6 matrices
  // aliases (consumer finished before producer writes):
  unsigned short* attn = vb_;   // vb last read by qkv gemm
  unsigned short* hy   = kb_;   // kb last read by qkv gemm
  unsigned short* ln1b = qb_;   // qb last read by qkv gemm
  unsigned short* f1   = Qp;    // Qp last read by attn
  unsigned short* y2   = Kp;    // Kp last read by attn

  cast3_kernel<<<dim3(MTOT * 512 / 2048, 3), 256, 0, stream>>>(q_in, k_in, v_in, qb_, kb_, vb_);
  transpose6_kernel<<<dim3(16, 16, 6), 256, 0, stream>>>(Wq, Wk, Wv, Wo, Wh, W2, Wt);

  // fused QKV projections (z: 0=Q,1=K,2=V-transposed)
  gemm_qkv_kernel<<<dim3(MTOT / 64, 8, 3), 256, 0, stream>>>(
      qb_, kb_, vb_, Wt, bq, bk, bv, Qp, Kp, Vt);

  // attention
  attn_kernel<<<dim3(BATCH * NH, 32), 256, 0, stream>>>(Qp, Kp, Vt, attn);

  dim3 gg(MTOT / 64, 8);
  // hy = bf16(attn @ Wo + bo + q)
  gemm_kernel<EPI_RESF32><<<gg, 256, 0, stream>>>(attn, Wt + 3 * 512 * 512, bo, q_in, hy);
  lnb_kernel<0><<<MTOT / 4, 256, 0, stream>>>(hy, g1, be1, nullptr, ln1b);
  // f1 = leaky(ln1 @ Wh + bh)
  gemm_kernel<EPI_LRELU><<<gg, 256, 0, stream>>>(ln1b, Wt + 4 * 512 * 512, bh, nullptr, f1);
  // y2 = bf16(f1 @ W2 + b2 + ln1)
  gemm_kernel<EPI_RESB16><<<gg, 256, 0, stream>>>(f1, Wt + 5 * 512 * 512, b2, ln1b, y2);
  lnb_kernel<1><<<MTOT / 4, 256, 0, stream>>>(y2, g2, be2, (float*)d_out, nullptr);
}